// Round 1
// baseline (3285.941 us; speedup 1.0000x reference)
//
#include <hip/hip_runtime.h>
#include <hip/hip_bf16.h>
#include <math.h>

#define VB 50000
#define EE 256
#define UU 512
#define BB 256
#define TT 256
#define G4 2048
#define NEGW (-(1 << 30))

typedef __attribute__((ext_vector_type(8))) short short8;
typedef __attribute__((ext_vector_type(4))) float f32x4;

__device__ __forceinline__ float sigf(float x){ return 1.0f/(1.0f+expf(-x)); }
__device__ __forceinline__ unsigned short f2bf(float f){
    __hip_bfloat16 h = __float2bfloat16(f);   // RNE
    unsigned short s; __builtin_memcpy(&s,&h,2); return s;
}
__device__ __forceinline__ float bf2f(unsigned short u){
    unsigned int x = ((unsigned int)u)<<16; float f; __builtin_memcpy(&f,&x,4); return f;
}

// 16-byte device-coherent load as 2x8B agent-scope relaxed atomics (bypass
// stale per-CU L1 / per-XCD L2; served at the coherent point).
struct AF { unsigned long long a, b; };
__device__ __forceinline__ AF cload16(const unsigned short* p){
    const unsigned long long* q = (const unsigned long long*)p;
    AF r;
    r.a = __hip_atomic_load(q,   __ATOMIC_RELAXED, __HIP_MEMORY_SCOPE_AGENT);
    r.b = __hip_atomic_load(q+1, __ATOMIC_RELAXED, __HIP_MEMORY_SCOPE_AGENT);
    return r;
}
__device__ __forceinline__ short8 af2v(AF x){
    union { unsigned long long u[2]; short8 v; } c; c.u[0]=x.a; c.u[1]=x.b; return c.v;
}

// Poll the packed {cntL0 | cntL1<<32} epoch counter until both thresholds met.
// All lanes load the same 8B address -> one LLC transaction per wave per round.
__device__ __forceinline__ void waitcnt2(const unsigned long long* c, int thr0, int thr1){
    if (thr0 <= 0 && thr1 <= 0) return;
    for (;;) {
        unsigned long long v = __hip_atomic_load(c, __ATOMIC_RELAXED, __HIP_MEMORY_SCOPE_AGENT);
        if ((int)(unsigned int)v >= thr0 && (int)(unsigned int)(v >> 32) >= thr1) break;
        __builtin_amdgcn_s_sleep(1);
    }
}

// ---------- pre-pass: transpose+convert W [rows][2048] fp32 -> out[c][koff+k] bf16 ----------
__global__ __launch_bounds__(256) void wtrans(const float* __restrict__ in, int rows,
                                              unsigned short* __restrict__ out,
                                              int Kout, int koff) {
    __shared__ float tl[32][33];
    int tx = threadIdx.x, ty = threadIdx.y;
    int c0 = blockIdx.x * 32, k0 = blockIdx.y * 32;
    #pragma unroll
    for (int i = 0; i < 4; i++)
        tl[ty + i * 8][tx] = in[(size_t)(k0 + ty + i * 8) * G4 + c0 + tx];
    __syncthreads();
    #pragma unroll
    for (int i = 0; i < 4; i++)
        out[(size_t)(c0 + ty + i * 8) * Kout + koff + k0 + tx] = f2bf(tl[tx][ty + i * 8]);
}

// ---------- pre-pass: gather embeddings -> xbf[t][b][k] bf16 ----------
__global__ __launch_bounds__(64) void xgather(const int* __restrict__ tokens,
                                              const float* __restrict__ emb,
                                              unsigned short* __restrict__ xbf) {
    int flat = blockIdx.x;
    int b = flat & 255, t = flat >> 8;
    int tok = tokens[b * TT + t];
    float4 v = ((const float4*)(emb + (size_t)tok * EE))[threadIdx.x];
    ushort4 o;
    o.x = f2bf(v.x); o.y = f2bf(v.y); o.z = f2bf(v.z); o.w = f2bf(v.w);
    ((ushort4*)(xbf + ((size_t)t * BB + b) * EE))[threadIdx.x] = o;
}

// ---------- persistent 2-layer LSTM ----------
// 4 groups x 64 blocks; group g owns batch rows [g*64, g*64+64).
// local 0..31 = layer0 (K=768: x|h0), 32..63 = layer1 (K=1024: h0|h1); 16 u's/block.
// Sync: ONE u64 per group = {sum of L0 arrivals | sum of L1 arrivals}. Sum
// threshold c >= 32*p  <=>  all 32 blocks of that layer arrived at iter p
// (first-hit argument: arrival p+1 is gated on c >= 32p, so when the sum
// first reaches 32p every block is exactly at p).
// MFMA operands are SWAPPED vs the classic layout (A = weight frag, B = x/h
// frag; fragments are lane-symmetric so the same loads serve both roles).
// D is therefore transposed: col = n16 = batch, row = q*4+r = unit. Each
// thread then owns 4 CONSECUTIVE units of one batch row -> h store is a
// single packed 8B agent-scope store; no LDS staging, no extra barrier.
// A-loads: ALL chunks in flight (16 for L0, 16+16 for L1) -> one exposed
// LLC latency per phase. L1 splits its wait: cntL0 (h0 ready, usually
// instant) -> issue h0 loads -> cntL1 (the binding wait, loads in flight
// underneath) -> issue h1 loads -> MFMA.
__global__ __launch_bounds__(256, 1) void rnn_persist(
    const unsigned short* __restrict__ Wt0,   // [2048][768]  bf16 [col][k]
    const unsigned short* __restrict__ Wt1,   // [2048][1024]
    const unsigned short* __restrict__ xbf,   // [256][256][256] bf16 (or unused)
    const int* __restrict__ tokens, const float* __restrict__ emb,
    const float* __restrict__ b0v, const float* __restrict__ b1v,
    unsigned short* __restrict__ h0buf,       // [4][256][512] bf16 ring
    unsigned short* __restrict__ h1buf,       // [2][256][512] bf16 ring
    unsigned int* __restrict__ bars,          // per group: u64 counter (1KB stride)
    int use_xbf)
{
    extern __shared__ char smem[];
    unsigned short* wl  = (unsigned short*)smem;        // frag-ordered weights (<=128KB)
    int*            tokl = (int*)(smem + 131072);       // 64 ints (non-xbf path)

    const int tid   = threadIdx.x;
    const int bid   = blockIdx.x;
    const int g     = bid >> 6;
    const int local = bid & 63;
    const int layer = local >> 5;
    const int u0    = (local & 31) * 16;
    const int row0  = g * 64;
    const int K     = layer ? 1024 : 768;
    const int KT    = K / 32;                  // 24 or 32 k-tiles
    const unsigned short* Wt = layer ? Wt1 : Wt0;
    const float* bR = layer ? b1v : b0v;

    // ---- fill LDS weights, frag-contiguous: chunk i = ((gate*KT+kt)*64 + (n*4+q)) ----
    const int nch = 4 * KT * 64;
    for (int i = tid; i < nch; i += 256) {
        int q2 = i & 3;
        int n  = (i >> 2) & 15;
        int t2 = i >> 6;
        int kt = t2 % KT, gate = t2 / KT;
        const unsigned short* src = Wt + (size_t)(gate * UU + u0 + n) * K + kt * 32 + q2 * 8;
        *(short8*)(wl + (size_t)i * 8) = *(const short8*)src;
    }

    const int lane = tid & 63;
    const int w    = tid >> 6;
    const int n16  = lane & 15;
    const int q    = lane >> 4;
    const int q8   = q * 8;
    const int myrow = row0 + w * 16 + n16;
    const unsigned short* wlane = wl + (n16 * 4 + q) * 8;   // + (gate*KT+kt)*512 shorts

    // bias per (gate, unit = u0 + q*4 + r)  -- D-transposed layout
    float gb4[4][4];
    #pragma unroll
    for (int gate = 0; gate < 4; gate++)
        #pragma unroll
        for (int r = 0; r < 4; r++)
            gb4[gate][r] = bR[gate * UU + u0 + q * 4 + r];
    float cst[4] = {0.f, 0.f, 0.f, 0.f};

    unsigned long long* cnt = (unsigned long long*)(bars + (size_t)g * 256);  // 1KB apart

    const size_t HS = (size_t)BB * UU;

    __syncthreads();   // wl ready

    for (int p = 0; p <= TT; p++) {
        f32x4 acc[4];
        #pragma unroll
        for (int gate = 0; gate < 4; gate++)
            acc[gate] = (f32x4){gb4[gate][0], gb4[gate][1], gb4[gate][2], gb4[gate][3]};

        if (layer == 0) {
            if (p < TT) {
                const unsigned short* h0r = h0buf + (size_t)(p & 3) * HS;
                unsigned short*       hw  = h0buf + (size_t)((p + 1) & 3) * HS;

                // ---- x-part: issue loads (xbf) / full gather+MFMA (emb) BEFORE wait ----
                short8 xv[8];
                if (use_xbf) {
                    const unsigned short* xp = xbf + ((size_t)p * BB + myrow) * EE + q8;
                    #pragma unroll
                    for (int kt = 0; kt < 8; kt++)
                        xv[kt] = *(const short8*)(xp + kt * 32);
                } else {
                    if (tid < 64) tokl[tid] = tokens[(size_t)(row0 + tid) * TT + p];
                    __syncthreads();
                    const float* ep = emb + (size_t)tokl[w * 16 + n16] * EE + q8;
                    #pragma unroll
                    for (int kt = 0; kt < 8; kt++) {
                        float4 f0 = *(const float4*)(ep + kt * 32);
                        float4 f1 = *(const float4*)(ep + kt * 32 + 4);
                        union { unsigned short s[8]; short8 v; } u;
                        u.s[0]=f2bf(f0.x); u.s[1]=f2bf(f0.y); u.s[2]=f2bf(f0.z); u.s[3]=f2bf(f0.w);
                        u.s[4]=f2bf(f1.x); u.s[5]=f2bf(f1.y); u.s[6]=f2bf(f1.z); u.s[7]=f2bf(f1.w);
                        #pragma unroll
                        for (int gate = 0; gate < 4; gate++) {
                            short8 bv = *(const short8*)(wlane + (size_t)(gate * KT + kt) * 512);
                            acc[gate] = __builtin_amdgcn_mfma_f32_16x16x32_bf16(bv, u.v, acc[gate], 0, 0, 0);
                        }
                    }
                }

                // h0(p) ready: all L0 blocks arrived p
                waitcnt2(cnt, 32 * p, NEGW);

                // issue ALL 16 h-chunks (one exposed latency), then x-MFMAs hide it
                AF hb[16];
                const unsigned short* ah = h0r + (size_t)myrow * UU + q8;
                #pragma unroll
                for (int i = 0; i < 16; i++) hb[i] = cload16(ah + i * 32);

                if (use_xbf) {
                    #pragma unroll
                    for (int kt = 0; kt < 8; kt++) {
                        #pragma unroll
                        for (int gate = 0; gate < 4; gate++) {
                            short8 bv = *(const short8*)(wlane + (size_t)(gate * KT + kt) * 512);
                            acc[gate] = __builtin_amdgcn_mfma_f32_16x16x32_bf16(bv, xv[kt], acc[gate], 0, 0, 0);
                        }
                    }
                }
                #pragma unroll
                for (int i = 0; i < 16; i++) {
                    short8 av = af2v(hb[i]);
                    #pragma unroll
                    for (int gate = 0; gate < 4; gate++) {
                        short8 bv = *(const short8*)(wlane + (size_t)(gate * KT + 8 + i) * 512);
                        acc[gate] = __builtin_amdgcn_mfma_f32_16x16x32_bf16(bv, av, acc[gate], 0, 0, 0);
                    }
                }

                // gating (D^T layout: col=n16 -> batch, row=q*4+r -> unit)
                unsigned long long pk = 0;
                #pragma unroll
                for (int r = 0; r < 4; r++) {
                    float zi = acc[0][r];
                    float zf = acc[1][r];
                    float zg = acc[2][r];
                    float zo = acc[3][r];
                    float cn = sigf(zf) * cst[r] + sigf(zi) * tanhf(zg);
                    cst[r] = cn;
                    pk |= (unsigned long long)f2bf(sigf(zo) * tanhf(cn)) << (16 * r);
                }
                // ring safety only for the OVERWRITE of h0(p-3): L1 done iter p-3
                waitcnt2(cnt, NEGW, 32 * (p - 2));
                __hip_atomic_store((unsigned long long*)(hw + (size_t)myrow * UU + u0 + q * 4),
                                   pk, __ATOMIC_RELAXED, __HIP_MEMORY_SCOPE_AGENT);
            }
        } else {
            if (p >= 1) {
                const unsigned short* h0r = h0buf + (size_t)(p & 3) * HS;        // h0(p)
                const unsigned short* h1r = h1buf + (size_t)((p + 1) & 1) * HS;  // h1(p-1)
                unsigned short*       hw  = h1buf + (size_t)(p & 1) * HS;        // h1(p)

                // phase A: h0(p) ready (L0 runs ahead -> usually instant)
                waitcnt2(cnt, 32 * p, NEGW);
                AF ha[16];
                const unsigned short* a0 = h0r + (size_t)myrow * UU + q8;
                #pragma unroll
                for (int i = 0; i < 16; i++) ha[i] = cload16(a0 + i * 32);

                // phase B: h1(p-1) ready (the binding wait; h0 loads in flight)
                waitcnt2(cnt, NEGW, 32 * p);
                AF hc[16];
                const unsigned short* a1 = h1r + (size_t)myrow * UU + q8;
                #pragma unroll
                for (int i = 0; i < 16; i++) hc[i] = cload16(a1 + i * 32);

                #pragma unroll
                for (int i = 0; i < 16; i++) {
                    short8 av = af2v(ha[i]);
                    #pragma unroll
                    for (int gate = 0; gate < 4; gate++) {
                        short8 bv = *(const short8*)(wlane + (size_t)(gate * KT + i) * 512);
                        acc[gate] = __builtin_amdgcn_mfma_f32_16x16x32_bf16(bv, av, acc[gate], 0, 0, 0);
                    }
                }
                #pragma unroll
                for (int i = 0; i < 16; i++) {
                    short8 av = af2v(hc[i]);
                    #pragma unroll
                    for (int gate = 0; gate < 4; gate++) {
                        short8 bv = *(const short8*)(wlane + (size_t)(gate * KT + 16 + i) * 512);
                        acc[gate] = __builtin_amdgcn_mfma_f32_16x16x32_bf16(bv, av, acc[gate], 0, 0, 0);
                    }
                }

                unsigned long long pk = 0;
                #pragma unroll
                for (int r = 0; r < 4; r++) {
                    float zi = acc[0][r];
                    float zf = acc[1][r];
                    float zg = acc[2][r];
                    float zo = acc[3][r];
                    float cn = sigf(zf) * cst[r] + sigf(zi) * tanhf(zg);
                    cst[r] = cn;
                    pk |= (unsigned long long)f2bf(sigf(zo) * tanhf(cn)) << (16 * r);
                }
                __hip_atomic_store((unsigned long long*)(hw + (size_t)myrow * UU + u0 + q * 4),
                                   pk, __ATOMIC_RELAXED, __HIP_MEMORY_SCOPE_AGENT);
            }
        }

        // ---- arrive(p): each wave drains its own stores; one add per block ----
        if (p < TT) {
            asm volatile("s_waitcnt vmcnt(0)" ::: "memory");
            __syncthreads();
            if (tid == 0)
                __hip_atomic_fetch_add((unsigned int*)cnt + layer, 1u,
                                       __ATOMIC_RELAXED, __HIP_MEMORY_SCOPE_AGENT);
        }
    }
}

// ---------- final dense: out[b] = sigmoid(h1 . Wd + bd) ----------
__global__ __launch_bounds__(64) void dense_out(
    const unsigned short* __restrict__ h, const float* __restrict__ Wd,
    const float* __restrict__ bd, float* __restrict__ out)
{
    int b = blockIdx.x;
    int lane = threadIdx.x;
    float s = 0.f;
    #pragma unroll
    for (int k = lane; k < UU; k += 64) s += bf2f(h[(size_t)b * UU + k]) * Wd[k];
    #pragma unroll
    for (int off = 32; off > 0; off >>= 1) s += __shfl_down(s, off);
    if (lane == 0) out[b] = sigf(s + bd[0]);
}

extern "C" void kernel_launch(void* const* d_in, const int* in_sizes, int n_in,
                              void* d_out, int out_size, void* d_ws, size_t ws_size,
                              hipStream_t stream) {
    const int*   tokens = (const int*)  d_in[0];
    const float* emb    = (const float*)d_in[1];
    const float* W0     = (const float*)d_in[2];
    const float* U0     = (const float*)d_in[3];
    const float* b0     = (const float*)d_in[4];
    const float* W1     = (const float*)d_in[5];
    const float* U1     = (const float*)d_in[6];
    const float* b1     = (const float*)d_in[7];
    const float* Wd     = (const float*)d_in[8];
    const float* bd     = (const float*)d_in[9];
    float* out = (float*)d_out;

    // ws layout (bytes):
    // [Wt0 3MB][Wt1 4MB][h0 ring x4 1MB][h1 ring x2 0.5MB][bars 32KB][xbf 32MB]
    const size_t oWt0 = 0;
    const size_t oWt1 = (size_t)G4 * 768 * 2;                 // 3,145,728
    const size_t oH0  = oWt1 + (size_t)G4 * 1024 * 2;         // 7,340,032
    const size_t oH1  = oH0 + (size_t)4 * BB * UU * 2;        // +1,048,576
    const size_t oBar = oH1 + (size_t)2 * BB * UU * 2;        // +524,288
    const size_t oX   = oBar + 32768;
    const size_t needFull = oX + (size_t)TT * BB * EE * 2;    // ~42.5 MB
    int use_xbf = (ws_size >= needFull) ? 1 : 0;

    unsigned short* Wt0p = (unsigned short*)((char*)d_ws + oWt0);
    unsigned short* Wt1p = (unsigned short*)((char*)d_ws + oWt1);
    unsigned short* h0p  = (unsigned short*)((char*)d_ws + oH0);
    unsigned short* h1p  = (unsigned short*)((char*)d_ws + oH1);
    unsigned int*   barp = (unsigned int*)  ((char*)d_ws + oBar);
    unsigned short* xbfp = (unsigned short*)((char*)d_ws + oX);

    hipMemsetAsync((char*)d_ws + oH0, 0, oX - oH0, stream);

    wtrans<<<dim3(G4 / 32, EE / 32), dim3(32, 8), 0, stream>>>(W0, EE, Wt0p, 768, 0);
    wtrans<<<dim3(G4 / 32, UU / 32), dim3(32, 8), 0, stream>>>(U0, UU, Wt0p, 768, 256);
    wtrans<<<dim3(G4 / 32, UU / 32), dim3(32, 8), 0, stream>>>(W1, UU, Wt1p, 1024, 0);
    wtrans<<<dim3(G4 / 32, UU / 32), dim3(32, 8), 0, stream>>>(U1, UU, Wt1p, 1024, 512);

    if (use_xbf)
        xgather<<<dim3(BB * TT), dim3(64), 0, stream>>>(tokens, emb, xbfp);

    {
        const size_t shmem = 131072 + 256;   // wl + tokl
        hipFuncSetAttribute((const void*)rnn_persist,
                            hipFuncAttributeMaxDynamicSharedMemorySize, (int)shmem);
        void* args[] = {(void*)&Wt0p, (void*)&Wt1p, (void*)&xbfp,
                        (void*)&tokens, (void*)&emb, (void*)&b0, (void*)&b1,
                        (void*)&h0p, (void*)&h1p, (void*)&barp, (void*)&use_xbf};
        hipLaunchCooperativeKernel((const void*)rnn_persist, dim3(256), dim3(256),
                                   args, shmem, stream);
    }

    dense_out<<<dim3(BB), dim3(64), 0, stream>>>(h1p, Wd, bd, out);   // h1(256) = slot 0
}